// Round 1
// baseline (11703.041 us; speedup 1.0000x reference)
//
#include <hip/hip_runtime.h>

#define USER_NUM 100000
#define ITEM_NUM 50000
#define N_NODES  150000
#define EMB      64
#define NNZ_TOTAL 6400000
#define MATF ((size_t)N_NODES * EMB)   // 9,600,000 floats per matrix

// ---------------------------------------------------------------------------
// Threefry-2x32, 20 rounds (Random123 / JAX-compatible).
// ---------------------------------------------------------------------------
__host__ __device__ __forceinline__ void tf_block(unsigned k0, unsigned k1,
                                                  unsigned x0, unsigned x1,
                                                  unsigned& o0, unsigned& o1) {
    unsigned ks[3] = {k0, k1, k0 ^ k1 ^ 0x1BD11BDAu};
    unsigned X0 = x0 + ks[0];
    unsigned X1 = x1 + ks[1];
    const int R[2][4] = {{13, 15, 26, 6}, {17, 29, 16, 24}};
#pragma unroll
    for (int i = 0; i < 5; ++i) {
        const int* r = R[i & 1];
#pragma unroll
        for (int j = 0; j < 4; ++j) {
            X0 += X1;
            X1 = (X1 << r[j]) | (X1 >> (32 - r[j]));
            X1 ^= X0;
        }
        X0 += ks[(i + 1) % 3];
        X1 += ks[(i + 2) % 3] + (unsigned)(i + 1);
    }
    o0 = X0; o1 = X1;
}

// ---------------------------------------------------------------------------
// SpMM, layer 0: gathers straight from the (virtually concatenated) inputs.
// One wave (64 lanes) per edge; lane == embedding dim.
// ---------------------------------------------------------------------------
__global__ __launch_bounds__(256) void spmm3_first(
    const int* __restrict__ rows, const int* __restrict__ cols,
    const float* __restrict__ vals,
    const float* __restrict__ user, const float* __restrict__ item,
    const float* __restrict__ image, const float* __restrict__ text,
    float* __restrict__ de, float* __restrict__ di, float* __restrict__ dt) {
    unsigned gid = blockIdx.x * 256u + threadIdx.x;
    int e = (int)(gid >> 6);
    int lane = threadIdx.x & 63;
    if (e >= NNZ_TOTAL) return;
    int r = rows[e], c = cols[e];
    float v = vals[e];
    float se, si, st;
    if (c < USER_NUM) {
        float u = user[(size_t)c * EMB + lane];
        se = u; si = u; st = u;
    } else {
        size_t cc = (size_t)(c - USER_NUM) * EMB + lane;
        se = item[cc]; si = image[cc]; st = text[cc];
    }
    size_t ro = (size_t)r * EMB + lane;
    unsafeAtomicAdd(&de[ro], v * se);
    unsafeAtomicAdd(&di[ro], v * si);
    unsafeAtomicAdd(&dt[ro], v * st);
}

// SpMM, layers 1..2: sources are the ping-pong workspace matrices.
__global__ __launch_bounds__(256) void spmm3(
    const int* __restrict__ rows, const int* __restrict__ cols,
    const float* __restrict__ vals,
    const float* __restrict__ se_m, const float* __restrict__ si_m,
    const float* __restrict__ st_m,
    float* __restrict__ de, float* __restrict__ di, float* __restrict__ dt) {
    unsigned gid = blockIdx.x * 256u + threadIdx.x;
    int e = (int)(gid >> 6);
    int lane = threadIdx.x & 63;
    if (e >= NNZ_TOTAL) return;
    int r = rows[e], c = cols[e];
    float v = vals[e];
    size_t cc = (size_t)c * EMB + lane;
    size_t ro = (size_t)r * EMB + lane;
    unsafeAtomicAdd(&de[ro], v * se_m[cc]);
    unsafeAtomicAdd(&di[ro], v * si_m[cc]);
    unsafeAtomicAdd(&dt[ro], v * st_m[cc]);
}

// ---------------------------------------------------------------------------
// Per-row post-process: leaky-relu + threefry dropout (written back: feeds the
// next layer's SpMM), row l2norm (64-lane shuffle reduce), and accumulation of
// this layer's contribution straight into d_out.
// out layout: [0, USER_NUM*64)   = user_all  (ego only)
//             [USER_NUM*64, end) = item_all  (w0*ego + w1*nimg + w2*ntxt)
// ---------------------------------------------------------------------------
__global__ __launch_bounds__(256) void postproc(
    float* __restrict__ e_mat, float* __restrict__ i_mat, float* __restrict__ t_mat,
    const float* __restrict__ w, float* __restrict__ out,
    unsigned ki0, unsigned ki1, unsigned kt0, unsigned kt1) {
    unsigned gid = blockIdx.x * 256u + threadIdx.x;
    int row = (int)(gid >> 6);
    int lane = threadIdx.x & 63;
    if (row >= N_NODES) return;
    size_t idx = (size_t)row * EMB + lane;
    unsigned j = (unsigned)idx;  // flat element index, < 9.6M

    float ev = e_mat[idx];

    unsigned y0, y1;
    float iv = i_mat[idx];
    iv = iv >= 0.0f ? iv : 0.01f * iv;          // leaky_relu
    tf_block(ki0, ki1, 0u, j, y0, y1);
    iv = ((y0 ^ y1) >> 31) ? 0.0f : iv * 2.0f;  // keep iff uniform<0.5 (MSB==0)
    i_mat[idx] = iv;                            // next layer's input

    float tv = t_mat[idx];
    tv = tv >= 0.0f ? tv : 0.01f * tv;
    tf_block(kt0, kt1, 0u, j, y0, y1);
    tv = ((y0 ^ y1) >> 31) ? 0.0f : tv * 2.0f;
    t_mat[idx] = tv;

    // row-wise sum of squares across the 64 lanes
    float si = iv * iv, st = tv * tv;
#pragma unroll
    for (int m = 1; m < 64; m <<= 1) {
        si += __shfl_xor(si, m, 64);
        st += __shfl_xor(st, m, 64);
    }
    float ni = iv / fmaxf(sqrtf(si), 1e-12f);
    float nt = tv / fmaxf(sqrtf(st), 1e-12f);

    const float inv3 = 1.0f / 3.0f;
    if (row < USER_NUM) {
        out[idx] += ev * inv3;
    } else {
        size_t oi = (size_t)USER_NUM * EMB + (size_t)(row - USER_NUM) * EMB + lane;
        out[oi] += (w[0] * ev + w[1] * ni + w[2] * nt) * inv3;
    }
}

// ---------------------------------------------------------------------------
extern "C" void kernel_launch(void* const* d_in, const int* in_sizes, int n_in,
                              void* d_out, int out_size, void* d_ws, size_t ws_size,
                              hipStream_t stream) {
    const float* user  = (const float*)d_in[0];
    const float* item  = (const float*)d_in[1];
    const float* image = (const float*)d_in[2];
    const float* text  = (const float*)d_in[3];
    const float* w     = (const float*)d_in[4];
    const float* vals  = (const float*)d_in[5];
    const int*   rows  = (const int*)d_in[6];
    const int*   cols  = (const int*)d_in[7];
    float* out = (float*)d_out;

    // workspace: two ping-pong triples (e,i,t each MATF floats), contiguous
    float* A = (float*)d_ws;          // matrices 0..2
    float* B = A + 3 * MATF;          // matrices 3..5

    hipMemsetAsync(out, 0, (size_t)out_size * sizeof(float), stream);

    const int spmm_blocks = (int)(((size_t)NNZ_TOTAL * 64) / 256);  // 1.6M
    const int pp_blocks   = (int)((MATF + 255) / 256);              // 37500

    float* cur = nullptr;
    float* nxt = B;
    for (int k = 0; k < 3; ++k) {
        hipMemsetAsync(nxt, 0, 3 * MATF * sizeof(float), stream);
        if (k == 0) {
            spmm3_first<<<spmm_blocks, 256, 0, stream>>>(
                rows, cols, vals, user, item, image, text,
                nxt, nxt + MATF, nxt + 2 * MATF);
        } else {
            spmm3<<<spmm_blocks, 256, 0, stream>>>(
                rows, cols, vals, cur, cur + MATF, cur + 2 * MATF,
                nxt, nxt + MATF, nxt + 2 * MATF);
        }
        // JAX threefry key schedule for layer k (host-side):
        // folded = block(key(42), (0,k)); ki = block(folded,(0,0)); kt = block(folded,(0,1))
        unsigned f0, f1, a0, a1, b0, b1;
        tf_block(0u, 42u, 0u, (unsigned)k, f0, f1);
        tf_block(f0, f1, 0u, 0u, a0, a1);
        tf_block(f0, f1, 0u, 1u, b0, b1);
        postproc<<<pp_blocks, 256, 0, stream>>>(
            nxt, nxt + MATF, nxt + 2 * MATF, w, out, a0, a1, b0, b1);

        float* prevCur = cur;
        cur = nxt;
        nxt = (k == 0) ? A : prevCur;
    }
}

// Round 4
// 2286.758 us; speedup vs baseline: 5.1177x; 5.1177x over previous
//
#include <hip/hip_runtime.h>
#include <hip/hip_bf16.h>

#define USER_NUM 100000
#define N_NODES  150000
#define EMB      64
#define NNZ      6400000
#define MATF ((size_t)N_NODES * EMB)   // floats per matrix (9.6M)

// ---------------------------------------------------------------------------
// Threefry-2x32, 20 rounds (JAX-compatible; verified passing in round 1).
// ---------------------------------------------------------------------------
__host__ __device__ __forceinline__ void tf_block(unsigned k0, unsigned k1,
                                                  unsigned x0, unsigned x1,
                                                  unsigned& o0, unsigned& o1) {
    unsigned ks[3] = {k0, k1, k0 ^ k1 ^ 0x1BD11BDAu};
    unsigned X0 = x0 + ks[0];
    unsigned X1 = x1 + ks[1];
    const int R[2][4] = {{13, 15, 26, 6}, {17, 29, 16, 24}};
#pragma unroll
    for (int i = 0; i < 5; ++i) {
        const int* r = R[i & 1];
#pragma unroll
        for (int j = 0; j < 4; ++j) {
            X0 += X1;
            X1 = (X1 << r[j]) | (X1 >> (32 - r[j]));
            X1 ^= X0;
        }
        X0 += ks[(i + 1) % 3];
        X1 += ks[(i + 2) % 3] + (unsigned)(i + 1);
    }
    o0 = X0; o1 = X1;
}

// ---------------------------------------------------------------------------
// CSR build, all in ONE int array `cur` (N_NODES):
//   memset 0 -> histogram -> in-place exclusive scan -> scatter (atomicAdd).
// After scatter, cur[i] == end offset of row i (cur[i-1] == begin).
// ---------------------------------------------------------------------------
__global__ __launch_bounds__(256) void hist_k(const int* __restrict__ rows,
                                              int* __restrict__ deg) {
    int e = blockIdx.x * 256 + threadIdx.x;
    if (e < NNZ) atomicAdd(&deg[rows[e]], 1);
}

#define SCAN_T 1024
#define CHUNK  ((N_NODES + SCAN_T - 1) / SCAN_T)   // 147
__global__ __launch_bounds__(SCAN_T) void scan_k(int* __restrict__ a) {
    __shared__ int sh[SCAN_T];
    int t = threadIdx.x;
    int lo = t * CHUNK;
    int hi = lo + CHUNK < N_NODES ? lo + CHUNK : N_NODES;
    int s = 0;
    for (int i = lo; i < hi; ++i) s += a[i];
    sh[t] = s;
    __syncthreads();
    for (int off = 1; off < SCAN_T; off <<= 1) {
        int x = (t >= off) ? sh[t - off] : 0;
        __syncthreads();
        sh[t] += x;
        __syncthreads();
    }
    int run = sh[t] - s;  // exclusive prefix of this chunk
    for (int i = lo; i < hi; ++i) {
        int d = a[i];      // read BEFORE overwrite (in-place)
        a[i] = run;
        run += d;
    }
}

__global__ __launch_bounds__(256) void scatter_k(const int* __restrict__ rows,
                                                 const int* __restrict__ cols,
                                                 const float* __restrict__ vals,
                                                 int* __restrict__ cur,
                                                 int2* __restrict__ edges) {
    int e = blockIdx.x * 256 + threadIdx.x;
    if (e >= NNZ) return;
    int pos = atomicAdd(&cur[rows[e]], 1);
    edges[pos] = make_int2(cols[e], __float_as_int(vals[e]));
}

// ---------------------------------------------------------------------------
// Fused SpMM (3 matrices) + leaky-relu + threefry dropout + l2norm + output
// accumulation. One wave per row; lane == embedding dim. No float atomics.
// E matrices are f32; I/T matrices are stored bf16 (write-back only; the
// norm/output math uses full f32).
// ---------------------------------------------------------------------------
template <bool FIRST>
__global__ __launch_bounds__(256) void spmm_post(
    const int* __restrict__ cur, const int2* __restrict__ edges,
    const float* __restrict__ sE, const __hip_bfloat16* __restrict__ sI,
    const __hip_bfloat16* __restrict__ sT,
    const float* __restrict__ user, const float* __restrict__ item,
    const float* __restrict__ image, const float* __restrict__ text,
    float* __restrict__ dE, __hip_bfloat16* __restrict__ dI,
    __hip_bfloat16* __restrict__ dT,
    const float* __restrict__ w, float* __restrict__ out,
    unsigned ki0, unsigned ki1, unsigned kt0, unsigned kt1, int writeBack) {
    int row = (int)((blockIdx.x * 256u + threadIdx.x) >> 6);
    int lane = threadIdx.x & 63;
    if (row >= N_NODES) return;
    int beg = (row == 0) ? 0 : cur[row - 1];
    int end = cur[row];
    float ae = 0.f, ai = 0.f, at = 0.f;
#pragma unroll 4
    for (int i = beg; i < end; ++i) {
        int2 cv = edges[i];            // wave-uniform 8B broadcast load
        int c = cv.x;
        float v = __int_as_float(cv.y);
        float xe, xi, xt;
        if (FIRST) {
            if (c < USER_NUM) {
                float u = user[(size_t)c * EMB + lane];
                xe = u; xi = u; xt = u;
            } else {
                size_t cc = (size_t)(c - USER_NUM) * EMB + lane;
                xe = item[cc]; xi = image[cc]; xt = text[cc];
            }
        } else {
            size_t cc = (size_t)c * EMB + lane;
            xe = sE[cc];
            xi = __bfloat162float(sI[cc]);
            xt = __bfloat162float(sT[cc]);
        }
        ae += v * xe; ai += v * xi; at += v * xt;
    }

    size_t idx = (size_t)row * EMB + lane;
    unsigned j = (unsigned)idx;

    float iv = ai >= 0.f ? ai : 0.01f * ai;      // leaky_relu
    float tv = at >= 0.f ? at : 0.01f * at;
    unsigned y0, y1;
    tf_block(ki0, ki1, 0u, j, y0, y1);
    iv = ((y0 ^ y1) >> 31) ? 0.f : iv * 2.f;     // dropout p=0.5, keep iff MSB==0
    tf_block(kt0, kt1, 0u, j, y0, y1);
    tv = ((y0 ^ y1) >> 31) ? 0.f : tv * 2.f;

    if (writeBack) {                              // next layer's SpMM inputs
        dE[idx] = ae;
        dI[idx] = __float2bfloat16(iv);
        dT[idx] = __float2bfloat16(tv);
    }

    // row-wise l2 norms across the 64 lanes (full f32 values)
    float si = iv * iv, st = tv * tv;
#pragma unroll
    for (int m = 1; m < 64; m <<= 1) {
        si += __shfl_xor(si, m, 64);
        st += __shfl_xor(st, m, 64);
    }
    float ni = iv / fmaxf(sqrtf(si), 1e-12f);
    float nt = tv / fmaxf(sqrtf(st), 1e-12f);

    const float inv3 = 1.0f / 3.0f;
    // out is row-major over all 150K rows (user_all ++ item_all contiguous)
    if (row < USER_NUM) {
        out[idx] += ae * inv3;
    } else {
        out[idx] += (w[0] * ae + w[1] * ni + w[2] * nt) * inv3;
    }
}

// ---------------------------------------------------------------------------
extern "C" void kernel_launch(void* const* d_in, const int* in_sizes, int n_in,
                              void* d_out, int out_size, void* d_ws, size_t ws_size,
                              hipStream_t stream) {
    const float* user  = (const float*)d_in[0];
    const float* item  = (const float*)d_in[1];
    const float* image = (const float*)d_in[2];
    const float* text  = (const float*)d_in[3];
    const float* w     = (const float*)d_in[4];
    const float* vals  = (const float*)d_in[5];
    const int*   rows  = (const int*)d_in[6];
    const int*   cols  = (const int*)d_in[7];
    float* out = (float*)d_out;

    // workspace layout (total ~205.4 MB)
    int2* edges = (int2*)d_ws;                               // NNZ * 8B
    float* eA   = (float*)(edges + NNZ);                     // E ping (f32)
    float* eB   = eA + MATF;                                 // E pong (f32)
    __hip_bfloat16* iA = (__hip_bfloat16*)(eB + MATF);       // I ping (bf16)
    __hip_bfloat16* iB = iA + MATF;                          // I pong
    __hip_bfloat16* tA = iB + MATF;                          // T ping
    __hip_bfloat16* tB = tA + MATF;                          // T pong
    int* cur = (int*)(tB + MATF);                            // N_NODES ints

    // ---- CSR build (counting sort by row), all in `cur` ----
    hipMemsetAsync(cur, 0, N_NODES * sizeof(int), stream);
    hist_k<<<NNZ / 256, 256, 0, stream>>>(rows, cur);
    scan_k<<<1, SCAN_T, 0, stream>>>(cur);
    scatter_k<<<NNZ / 256, 256, 0, stream>>>(rows, cols, vals, cur, edges);

    hipMemsetAsync(out, 0, (size_t)out_size * sizeof(float), stream);

    const int blocks = (int)((MATF + 255) / 256);  // 37500: one wave per row

    float* sE = nullptr; __hip_bfloat16* sI = nullptr; __hip_bfloat16* sT = nullptr;
    float* dE = eB;      __hip_bfloat16* dI = iB;      __hip_bfloat16* dT = tB;
    for (int k = 0; k < 3; ++k) {
        unsigned f0, f1, a0, a1, b0, b1;
        tf_block(0u, 42u, 0u, (unsigned)k, f0, f1);
        tf_block(f0, f1, 0u, 0u, a0, a1);
        tf_block(f0, f1, 0u, 1u, b0, b1);
        int writeBack = (k < 2) ? 1 : 0;
        if (k == 0) {
            spmm_post<true><<<blocks, 256, 0, stream>>>(
                cur, edges, nullptr, nullptr, nullptr,
                user, item, image, text,
                dE, dI, dT, w, out, a0, a1, b0, b1, writeBack);
        } else {
            spmm_post<false><<<blocks, 256, 0, stream>>>(
                cur, edges, sE, sI, sT,
                user, item, image, text,
                dE, dI, dT, w, out, a0, a1, b0, b1, writeBack);
        }
        // swap ping/pong
        float* pe = sE; __hip_bfloat16* pi = sI; __hip_bfloat16* pt = sT;
        sE = dE; sI = dI; sT = dT;
        dE = (k == 0) ? eA : pe;
        dI = (k == 0) ? iA : pi;
        dT = (k == 0) ? tA : pt;
    }
}

// Round 5
// 1895.106 us; speedup vs baseline: 6.1754x; 1.2067x over previous
//
#include <hip/hip_runtime.h>
#include <hip/hip_bf16.h>

#define USER_NUM 100000
#define N_NODES  150000
#define EMB      64
#define NNZ      6400000
#define MATF ((size_t)N_NODES * EMB)   // elems per matrix (9.6M)

// ---------------------------------------------------------------------------
// Threefry-2x32, 20 rounds (JAX-compatible; verified passing).
// ---------------------------------------------------------------------------
__host__ __device__ __forceinline__ void tf_block(unsigned k0, unsigned k1,
                                                  unsigned x0, unsigned x1,
                                                  unsigned& o0, unsigned& o1) {
    unsigned ks[3] = {k0, k1, k0 ^ k1 ^ 0x1BD11BDAu};
    unsigned X0 = x0 + ks[0];
    unsigned X1 = x1 + ks[1];
    const int R[2][4] = {{13, 15, 26, 6}, {17, 29, 16, 24}};
#pragma unroll
    for (int i = 0; i < 5; ++i) {
        const int* r = R[i & 1];
#pragma unroll
        for (int j = 0; j < 4; ++j) {
            X0 += X1;
            X1 = (X1 << r[j]) | (X1 >> (32 - r[j]));
            X1 ^= X0;
        }
        X0 += ks[(i + 1) % 3];
        X1 += ks[(i + 2) % 3] + (unsigned)(i + 1);
    }
    o0 = X0; o1 = X1;
}

__device__ __forceinline__ float bfu_to_f(unsigned short u) {
    return __uint_as_float((unsigned)u << 16);
}
__device__ __forceinline__ unsigned short f_to_bfu(float f) {
    __hip_bfloat16 b = __float2bfloat16(f);   // RNE
    return *(unsigned short*)&b;
}

// ---------------------------------------------------------------------------
// CSR build, all in ONE int array `cur` (N_NODES):
//   memset 0 -> histogram -> in-place exclusive scan -> scatter (atomicAdd).
// After scatter, cur[i] == end offset of row i (cur[i-1] == begin).
// ---------------------------------------------------------------------------
__global__ __launch_bounds__(256) void hist_k(const int* __restrict__ rows,
                                              int* __restrict__ deg) {
    int e = blockIdx.x * 256 + threadIdx.x;
    if (e < NNZ) atomicAdd(&deg[rows[e]], 1);
}

#define SCAN_T 1024
#define CHUNK  ((N_NODES + SCAN_T - 1) / SCAN_T)   // 147
__global__ __launch_bounds__(SCAN_T) void scan_k(int* __restrict__ a) {
    __shared__ int sh[SCAN_T];
    int t = threadIdx.x;
    int lo = t * CHUNK;
    int hi = lo + CHUNK < N_NODES ? lo + CHUNK : N_NODES;
    int s = 0;
    for (int i = lo; i < hi; ++i) s += a[i];
    sh[t] = s;
    __syncthreads();
    for (int off = 1; off < SCAN_T; off <<= 1) {
        int x = (t >= off) ? sh[t - off] : 0;
        __syncthreads();
        sh[t] += x;
        __syncthreads();
    }
    int run = sh[t] - s;  // exclusive prefix of this chunk
    for (int i = lo; i < hi; ++i) {
        int d = a[i];      // read BEFORE overwrite (in-place)
        a[i] = run;
        run += d;
    }
}

__global__ __launch_bounds__(256) void scatter_k(const int* __restrict__ rows,
                                                 const int* __restrict__ cols,
                                                 const float* __restrict__ vals,
                                                 int* __restrict__ cur,
                                                 int2* __restrict__ edges) {
    int e = blockIdx.x * 256 + threadIdx.x;
    if (e >= NNZ) return;
    int pos = atomicAdd(&cur[rows[e]], 1);
    edges[pos] = make_int2(cols[e], __float_as_int(vals[e]));
}

// ---------------------------------------------------------------------------
// Pack layer-0 sources: pE[row*64+lane] = bf16(ego), pIT = bf16(img)|bf16(txt)
// ---------------------------------------------------------------------------
__global__ __launch_bounds__(256) void pack0_k(
    const float* __restrict__ user, const float* __restrict__ item,
    const float* __restrict__ image, const float* __restrict__ text,
    unsigned short* __restrict__ pE, unsigned* __restrict__ pIT) {
    size_t idx = (size_t)blockIdx.x * 256 + threadIdx.x;
    if (idx >= MATF) return;
    int row = (int)(idx >> 6);
    float e, i, t;
    if (row < USER_NUM) {
        float u = user[idx];
        e = u; i = u; t = u;
    } else {
        size_t cc = idx - (size_t)USER_NUM * EMB;
        e = item[cc]; i = image[cc]; t = text[cc];
    }
    pE[idx]  = f_to_bfu(e);
    pIT[idx] = (unsigned)f_to_bfu(i) | ((unsigned)f_to_bfu(t) << 16);
}

// ---------------------------------------------------------------------------
// Fused SpMM (3 matrices, packed bf16 sources) + leaky-relu + threefry
// dropout + l2norm + output accumulation. One wave per row; lane == dim.
// ---------------------------------------------------------------------------
__global__ __launch_bounds__(256) void spmm_post(
    const int* __restrict__ cur, const int2* __restrict__ edges,
    const unsigned short* __restrict__ sE, const unsigned* __restrict__ sIT,
    unsigned short* __restrict__ dE, unsigned* __restrict__ dIT,
    const float* __restrict__ w, float* __restrict__ out,
    unsigned ki0, unsigned ki1, unsigned kt0, unsigned kt1, int writeBack) {
    int row = (int)((blockIdx.x * 256u + threadIdx.x) >> 6);
    int lane = threadIdx.x & 63;
    if (row >= N_NODES) return;
    int beg = __builtin_amdgcn_readfirstlane((row == 0) ? 0 : cur[row - 1]);
    int end = __builtin_amdgcn_readfirstlane(cur[row]);
    float ae = 0.f, ai = 0.f, at = 0.f;
#pragma unroll 8
    for (int i = beg; i < end; ++i) {
        int2 cv = edges[i];            // wave-uniform (scalar) 8B load
        size_t cc = (size_t)cv.x * EMB + lane;
        float v = __int_as_float(cv.y);
        float xe = bfu_to_f(sE[cc]);
        unsigned it = sIT[cc];
        float xi = __uint_as_float(it << 16);
        float xt = __uint_as_float(it & 0xffff0000u);
        ae += v * xe; ai += v * xi; at += v * xt;
    }

    size_t idx = (size_t)row * EMB + lane;
    unsigned j = (unsigned)idx;

    float iv = ai >= 0.f ? ai : 0.01f * ai;      // leaky_relu
    float tv = at >= 0.f ? at : 0.01f * at;
    unsigned y0, y1;
    tf_block(ki0, ki1, 0u, j, y0, y1);
    iv = ((y0 ^ y1) >> 31) ? 0.f : iv * 2.f;     // dropout p=0.5, keep iff MSB==0
    tf_block(kt0, kt1, 0u, j, y0, y1);
    tv = ((y0 ^ y1) >> 31) ? 0.f : tv * 2.f;

    if (writeBack) {                              // next layer's SpMM inputs
        dE[idx]  = f_to_bfu(ae);
        dIT[idx] = (unsigned)f_to_bfu(iv) | ((unsigned)f_to_bfu(tv) << 16);
    }

    // row-wise l2 norms across the 64 lanes (full f32 values)
    float si = iv * iv, st = tv * tv;
#pragma unroll
    for (int m = 1; m < 64; m <<= 1) {
        si += __shfl_xor(si, m, 64);
        st += __shfl_xor(st, m, 64);
    }
    float ni = iv / fmaxf(sqrtf(si), 1e-12f);
    float nt = tv / fmaxf(sqrtf(st), 1e-12f);

    const float inv3 = 1.0f / 3.0f;
    // out is row-major over all 150K rows (user_all ++ item_all contiguous)
    if (row < USER_NUM) {
        out[idx] += ae * inv3;
    } else {
        out[idx] += (w[0] * ae + w[1] * ni + w[2] * nt) * inv3;
    }
}

// ---------------------------------------------------------------------------
extern "C" void kernel_launch(void* const* d_in, const int* in_sizes, int n_in,
                              void* d_out, int out_size, void* d_ws, size_t ws_size,
                              hipStream_t stream) {
    const float* user  = (const float*)d_in[0];
    const float* item  = (const float*)d_in[1];
    const float* image = (const float*)d_in[2];
    const float* text  = (const float*)d_in[3];
    const float* w     = (const float*)d_in[4];
    const float* vals  = (const float*)d_in[5];
    const int*   rows  = (const int*)d_in[6];
    const int*   cols  = (const int*)d_in[7];
    float* out = (float*)d_out;

    // workspace layout (~167 MB)
    int2* edges = (int2*)d_ws;                               // NNZ * 8B
    unsigned short* eA = (unsigned short*)(edges + NNZ);     // E ping (bf16)
    unsigned short* eB = eA + MATF;                          // E pong
    unsigned* itA = (unsigned*)(eB + MATF);                  // IT ping (2xbf16)
    unsigned* itB = itA + MATF;                              // IT pong
    int* cur = (int*)(itB + MATF);                           // N_NODES ints

    // ---- CSR build (counting sort by row), all in `cur` ----
    hipMemsetAsync(cur, 0, N_NODES * sizeof(int), stream);
    hist_k<<<NNZ / 256, 256, 0, stream>>>(rows, cur);
    scan_k<<<1, SCAN_T, 0, stream>>>(cur);
    scatter_k<<<NNZ / 256, 256, 0, stream>>>(rows, cols, vals, cur, edges);

    hipMemsetAsync(out, 0, (size_t)out_size * sizeof(float), stream);

    const int blocks = (int)((MATF + 255) / 256);  // 37500: one wave per row
    pack0_k<<<blocks, 256, 0, stream>>>(user, item, image, text, eA, itA);

    unsigned short* sE = eA; unsigned* sIT = itA;
    unsigned short* dE = eB; unsigned* dIT = itB;
    for (int k = 0; k < 3; ++k) {
        unsigned f0, f1, a0, a1, b0, b1;
        tf_block(0u, 42u, 0u, (unsigned)k, f0, f1);
        tf_block(f0, f1, 0u, 0u, a0, a1);
        tf_block(f0, f1, 0u, 1u, b0, b1);
        int writeBack = (k < 2) ? 1 : 0;
        spmm_post<<<blocks, 256, 0, stream>>>(
            cur, edges, sE, sIT, dE, dIT, w, out, a0, a1, b0, b1, writeBack);
        // swap ping/pong
        unsigned short* te = sE; unsigned* tit = sIT;
        sE = dE; sIT = dIT;
        dE = te; dIT = tit;
    }
}

// Round 6
// 1812.443 us; speedup vs baseline: 6.4571x; 1.0456x over previous
//
#include <hip/hip_runtime.h>
#include <hip/hip_bf16.h>

#define USER_NUM 100000
#define N_NODES  150000
#define EMB      64
#define NNZ      6400000
#define MATF ((size_t)N_NODES * EMB)   // elems per matrix (9.6M)

#define RPB   32                        // rows per bucket
#define NBUCK ((N_NODES + RPB - 1) / RPB)   // 4688

// ---------------------------------------------------------------------------
// Threefry-2x32, 20 rounds (JAX-compatible; verified passing).
// ---------------------------------------------------------------------------
__host__ __device__ __forceinline__ void tf_block(unsigned k0, unsigned k1,
                                                  unsigned x0, unsigned x1,
                                                  unsigned& o0, unsigned& o1) {
    unsigned ks[3] = {k0, k1, k0 ^ k1 ^ 0x1BD11BDAu};
    unsigned X0 = x0 + ks[0];
    unsigned X1 = x1 + ks[1];
    const int R[2][4] = {{13, 15, 26, 6}, {17, 29, 16, 24}};
#pragma unroll
    for (int i = 0; i < 5; ++i) {
        const int* r = R[i & 1];
#pragma unroll
        for (int j = 0; j < 4; ++j) {
            X0 += X1;
            X1 = (X1 << r[j]) | (X1 >> (32 - r[j]));
            X1 ^= X0;
        }
        X0 += ks[(i + 1) % 3];
        X1 += ks[(i + 2) % 3] + (unsigned)(i + 1);
    }
    o0 = X0; o1 = X1;
}

__device__ __forceinline__ unsigned short f_to_bfu(float f) {
    __hip_bfloat16 b = __float2bfloat16(f);   // RNE
    return *(unsigned short*)&b;
}
__device__ __forceinline__ float bfu_to_f(unsigned short u) {
    return __uint_as_float((unsigned)u << 16);
}

// ---------------------------------------------------------------------------
// CSR build, bucketed two-pass counting sort (write-amplification-free).
//   bhist:    bcnt[b] = #edges with row in bucket b        (4688 counters, L2)
//   scan2:    exclusive scan -> bbase[] (starts, +sentinel) and bcur[] (cursors)
//   bscatter: tmp[atomic(bcur[b])++] = {col | row_local<<18, val}
//   bsort:    block per bucket: LDS 32-row hist+scan, write final edges +
//             per-row end offsets cur[]
// ---------------------------------------------------------------------------
__global__ __launch_bounds__(256) void bhist_k(const int* __restrict__ rows,
                                               int* __restrict__ bcnt) {
    int e = blockIdx.x * 256 + threadIdx.x;
    if (e < NNZ) atomicAdd(&bcnt[rows[e] >> 5], 1);
}

#define SCAN_T 1024
__global__ __launch_bounds__(SCAN_T) void scan2_k(int* __restrict__ a,
                                                  int* __restrict__ c, int n) {
    __shared__ int sh[SCAN_T];
    int t = threadIdx.x;
    int chunk = (n + SCAN_T - 1) / SCAN_T;
    int lo = t * chunk;
    int hi = lo + chunk < n ? lo + chunk : n;
    int s = 0;
    for (int i = lo; i < hi; ++i) s += a[i];
    sh[t] = s;
    __syncthreads();
    for (int off = 1; off < SCAN_T; off <<= 1) {
        int x = (t >= off) ? sh[t - off] : 0;
        __syncthreads();
        sh[t] += x;
        __syncthreads();
    }
    int run = sh[t] - s;  // exclusive prefix of this chunk
    for (int i = lo; i < hi; ++i) {
        int d = a[i];      // read BEFORE overwrite (in-place)
        a[i] = run;
        c[i] = run;
        run += d;
    }
    if (t == SCAN_T - 1) a[n] = sh[SCAN_T - 1];   // sentinel = total (NNZ)
}

__global__ __launch_bounds__(256) void bscatter_k(const int* __restrict__ rows,
                                                  const int* __restrict__ cols,
                                                  const float* __restrict__ vals,
                                                  int* __restrict__ bcur,
                                                  int2* __restrict__ tmp) {
    int e = blockIdx.x * 256 + threadIdx.x;
    if (e >= NNZ) return;
    int r = rows[e];
    int pos = atomicAdd(&bcur[r >> 5], 1);
    tmp[pos] = make_int2(cols[e] | ((r & 31) << 18), __float_as_int(vals[e]));
}

__global__ __launch_bounds__(256) void bsort_k(const int* __restrict__ bbase,
                                               const int2* __restrict__ tmp,
                                               int2* __restrict__ edges,
                                               int* __restrict__ cur) {
    __shared__ int h[RPB], st[RPB], inc[RPB];
    int b = blockIdx.x;
    int tid = threadIdx.x;
    int base = bbase[b];
    int cnt = bbase[b + 1] - base;
    if (tid < RPB) h[tid] = 0;
    __syncthreads();
    for (int i = tid; i < cnt; i += 256)
        atomicAdd(&h[(tmp[base + i].x >> 18) & 31], 1);
    __syncthreads();
    if (tid == 0) {
        int run = 0;
#pragma unroll
        for (int t = 0; t < RPB; ++t) {
            st[t] = base + run;
            run += h[t];
            inc[t] = base + run;
        }
    }
    __syncthreads();
    int r0 = b * RPB;
    if (tid < RPB && r0 + tid < N_NODES) cur[r0 + tid] = inc[tid];
    for (int i = tid; i < cnt; i += 256) {
        int2 w = tmp[base + i];
        int pos = atomicAdd(&st[(w.x >> 18) & 31], 1);
        edges[pos] = make_int2(w.x & 0x3FFFF, w.y);
    }
}

// ---------------------------------------------------------------------------
// Pack layer-0 sources: pE = bf16(ego), pIT = bf16(img) | bf16(txt)<<16
// ---------------------------------------------------------------------------
__global__ __launch_bounds__(256) void pack0_k(
    const float* __restrict__ user, const float* __restrict__ item,
    const float* __restrict__ image, const float* __restrict__ text,
    unsigned short* __restrict__ pE, unsigned* __restrict__ pIT) {
    size_t idx = (size_t)blockIdx.x * 256 + threadIdx.x;
    if (idx >= MATF) return;
    int row = (int)(idx >> 6);
    float e, i, t;
    if (row < USER_NUM) {
        float u = user[idx];
        e = u; i = u; t = u;
    } else {
        size_t cc = idx - (size_t)USER_NUM * EMB;
        e = item[cc]; i = image[cc]; t = text[cc];
    }
    pE[idx]  = f_to_bfu(e);
    pIT[idx] = (unsigned)f_to_bfu(i) | ((unsigned)f_to_bfu(t) << 16);
}

// ---------------------------------------------------------------------------
// Fused SpMM (3 matrices, packed bf16 sources) + leaky-relu + threefry
// dropout + l2norm + output accumulation. One wave per row; lane == dim.
// ---------------------------------------------------------------------------
__global__ __launch_bounds__(256) void spmm_post(
    const int* __restrict__ cur, const int2* __restrict__ edges,
    const unsigned short* __restrict__ sE, const unsigned* __restrict__ sIT,
    unsigned short* __restrict__ dE, unsigned* __restrict__ dIT,
    const float* __restrict__ w, float* __restrict__ out,
    unsigned ki0, unsigned ki1, unsigned kt0, unsigned kt1,
    int writeBack, int first) {
    int row = (int)((blockIdx.x * 256u + threadIdx.x) >> 6);
    int lane = threadIdx.x & 63;
    if (row >= N_NODES) return;
    int beg = __builtin_amdgcn_readfirstlane((row == 0) ? 0 : cur[row - 1]);
    int end = __builtin_amdgcn_readfirstlane(cur[row]);
    float ae = 0.f, ai = 0.f, at = 0.f;
#pragma unroll 8
    for (int i = beg; i < end; ++i) {
        int2 cv = edges[i];            // wave-uniform 8B load
        size_t cc = (size_t)cv.x * EMB + lane;
        float v = __int_as_float(cv.y);
        float xe = bfu_to_f(sE[cc]);
        unsigned it = sIT[cc];
        float xi = __uint_as_float(it << 16);
        float xt = __uint_as_float(it & 0xffff0000u);
        ae += v * xe; ai += v * xi; at += v * xt;
    }

    size_t idx = (size_t)row * EMB + lane;
    unsigned j = (unsigned)idx;

    float iv = ai >= 0.f ? ai : 0.01f * ai;      // leaky_relu
    float tv = at >= 0.f ? at : 0.01f * at;
    unsigned y0, y1;
    tf_block(ki0, ki1, 0u, j, y0, y1);
    iv = ((y0 ^ y1) >> 31) ? 0.f : iv * 2.f;     // dropout p=0.5, keep iff MSB==0
    tf_block(kt0, kt1, 0u, j, y0, y1);
    tv = ((y0 ^ y1) >> 31) ? 0.f : tv * 2.f;

    if (writeBack) {                              // next layer's SpMM inputs
        dE[idx]  = f_to_bfu(ae);
        dIT[idx] = (unsigned)f_to_bfu(iv) | ((unsigned)f_to_bfu(tv) << 16);
    }

    // row-wise l2 norms across the 64 lanes (full f32 values)
    float si = iv * iv, st2 = tv * tv;
#pragma unroll
    for (int m = 1; m < 64; m <<= 1) {
        si  += __shfl_xor(si, m, 64);
        st2 += __shfl_xor(st2, m, 64);
    }
    float ni = iv / fmaxf(sqrtf(si), 1e-12f);
    float nt = tv / fmaxf(sqrtf(st2), 1e-12f);

    const float inv3 = 1.0f / 3.0f;
    float contrib = (row < USER_NUM) ? ae * inv3
                                     : (w[0] * ae + w[1] * ni + w[2] * nt) * inv3;
    if (first) out[idx] = contrib;               // layer 0 overwrites (no memset)
    else       out[idx] += contrib;
}

// ---------------------------------------------------------------------------
extern "C" void kernel_launch(void* const* d_in, const int* in_sizes, int n_in,
                              void* d_out, int out_size, void* d_ws, size_t ws_size,
                              hipStream_t stream) {
    const float* user  = (const float*)d_in[0];
    const float* item  = (const float*)d_in[1];
    const float* image = (const float*)d_in[2];
    const float* text  = (const float*)d_in[3];
    const float* w     = (const float*)d_in[4];
    const float* vals  = (const float*)d_in[5];
    const int*   rows  = (const int*)d_in[6];
    const int*   cols  = (const int*)d_in[7];
    float* out = (float*)d_out;

    // workspace layout (~167 MB)
    int2* edges = (int2*)d_ws;                               // NNZ * 8B
    unsigned short* eA = (unsigned short*)(edges + NNZ);     // E ping (bf16)
    unsigned short* eB = eA + MATF;                          // E pong
    unsigned* itA = (unsigned*)(eB + MATF);                  // IT ping (2xbf16)
    unsigned* itB = itA + MATF;                              // IT pong
    int* cur   = (int*)(itB + MATF);                         // N_NODES ints
    int* bbase = cur + N_NODES;                              // NBUCK+1
    int* bcur  = bbase + (NBUCK + 1);                        // NBUCK
    // tmp bucket buffer aliased onto (eB, itA): dead until bsort_k completes,
    // first written (pack0/spmm0) strictly after bsort_k in stream order.
    int2* tmp = (int2*)eB;                                   // NNZ * 8B

    // ---- CSR build: bucketed counting sort ----
    hipMemsetAsync(bbase, 0, (NBUCK + 1) * sizeof(int), stream);
    bhist_k<<<NNZ / 256, 256, 0, stream>>>(rows, bbase);
    scan2_k<<<1, SCAN_T, 0, stream>>>(bbase, bcur, NBUCK);
    bscatter_k<<<NNZ / 256, 256, 0, stream>>>(rows, cols, vals, bcur, tmp);
    bsort_k<<<NBUCK, 256, 0, stream>>>(bbase, tmp, edges, cur);

    const int blocks = (int)((MATF + 255) / 256);  // 37500: one wave per row
    pack0_k<<<blocks, 256, 0, stream>>>(user, item, image, text, eA, itA);

    unsigned short* sE = eA; unsigned* sIT = itA;
    unsigned short* dE = eB; unsigned* dIT = itB;
    for (int k = 0; k < 3; ++k) {
        unsigned f0, f1, a0, a1, b0, b1;
        tf_block(0u, 42u, 0u, (unsigned)k, f0, f1);
        tf_block(f0, f1, 0u, 0u, a0, a1);
        tf_block(f0, f1, 0u, 1u, b0, b1);
        int writeBack = (k < 2) ? 1 : 0;
        spmm_post<<<blocks, 256, 0, stream>>>(
            cur, edges, sE, sIT, dE, dIT, w, out, a0, a1, b0, b1,
            writeBack, k == 0 ? 1 : 0);
        // swap ping/pong
        unsigned short* te = sE; unsigned* tit = sIT;
        sE = dE; sIT = dIT;
        dE = te; dIT = tit;
    }
}

// Round 7
// 1660.466 us; speedup vs baseline: 7.0480x; 1.0915x over previous
//
#include <hip/hip_runtime.h>
#include <hip/hip_bf16.h>

#define USER_NUM 100000
#define N_NODES  150000
#define EMB      64
#define NNZ      6400000
#define MATF ((size_t)N_NODES * EMB)   // elems per matrix (9.6M)

#define RPB1   512                      // rows per coarse bucket (row>>9)
#define NB1    ((N_NODES + RPB1 - 1) / RPB1)   // 293
#define CHUNK1 4096                     // edges staged per block in P1

// ---------------------------------------------------------------------------
// Threefry-2x32, 20 rounds (JAX-compatible; verified passing).
// ---------------------------------------------------------------------------
__host__ __device__ __forceinline__ void tf_block(unsigned k0, unsigned k1,
                                                  unsigned x0, unsigned x1,
                                                  unsigned& o0, unsigned& o1) {
    unsigned ks[3] = {k0, k1, k0 ^ k1 ^ 0x1BD11BDAu};
    unsigned X0 = x0 + ks[0];
    unsigned X1 = x1 + ks[1];
    const int R[2][4] = {{13, 15, 26, 6}, {17, 29, 16, 24}};
#pragma unroll
    for (int i = 0; i < 5; ++i) {
        const int* r = R[i & 1];
#pragma unroll
        for (int j = 0; j < 4; ++j) {
            X0 += X1;
            X1 = (X1 << r[j]) | (X1 >> (32 - r[j]));
            X1 ^= X0;
        }
        X0 += ks[(i + 1) % 3];
        X1 += ks[(i + 2) % 3] + (unsigned)(i + 1);
    }
    o0 = X0; o1 = X1;
}

__device__ __forceinline__ unsigned short f_to_bfu(float f) {
    __hip_bfloat16 b = __float2bfloat16(f);   // RNE
    return *(unsigned short*)&b;
}
__device__ __forceinline__ float bfu_to_f(unsigned short u) {
    return __uint_as_float((unsigned)u << 16);
}

// ---------------------------------------------------------------------------
// Per-row histogram (counters L2-resident) and in-place exclusive scan.
// After scan: rowbase[r] = start offset of row r; rowbase[N_NODES] = NNZ.
// ---------------------------------------------------------------------------
__global__ __launch_bounds__(256) void hist_row_k(const int* __restrict__ rows,
                                                  int* __restrict__ rowcnt) {
    int e = blockIdx.x * 256 + threadIdx.x;
    if (e < NNZ) atomicAdd(&rowcnt[rows[e]], 1);
}

#define SCAN_T 1024
#define SCHUNK ((N_NODES + SCAN_T - 1) / SCAN_T)   // 147
__global__ __launch_bounds__(SCAN_T) void scan_k(int* __restrict__ a) {
    __shared__ int sh[SCAN_T];
    int t = threadIdx.x;
    int lo = t * SCHUNK;
    int hi = lo + SCHUNK < N_NODES ? lo + SCHUNK : N_NODES;
    int s = 0;
    for (int i = lo; i < hi; ++i) s += a[i];
    sh[t] = s;
    __syncthreads();
    for (int off = 1; off < SCAN_T; off <<= 1) {
        int x = (t >= off) ? sh[t - off] : 0;
        __syncthreads();
        sh[t] += x;
        __syncthreads();
    }
    int run = sh[t] - s;  // exclusive prefix of this chunk
    for (int i = lo; i < hi; ++i) {
        int d = a[i];      // read BEFORE overwrite (in-place)
        a[i] = run;
        run += d;
    }
    if (t == SCAN_T - 1) a[N_NODES] = sh[SCAN_T - 1];   // sentinel = NNZ
}

__global__ __launch_bounds__(NB1) void binit_k(const int* __restrict__ rowbase,
                                               int* __restrict__ bcur) {
    int b = threadIdx.x;
    if (b < NB1) bcur[b] = rowbase[b * RPB1];
}

// ---------------------------------------------------------------------------
// P1: LDS-staged coarse scatter (write-combined). One block per 4096-edge
// chunk: LDS histogram over 293 buckets -> scan -> LDS reorder -> per-bucket
// global reservation -> flush bucket-contiguous runs (coalesced writes).
// tmp payload: x = col | (row & 511) << 18, y = bits(val).
// ---------------------------------------------------------------------------
__global__ __launch_bounds__(256) void p1_k(const int* __restrict__ rows,
                                            const int* __restrict__ cols,
                                            const float* __restrict__ vals,
                                            int* __restrict__ bcur,
                                            int2* __restrict__ tmp) {
    __shared__ int2 stage[CHUNK1];               // 32 KB
    __shared__ unsigned short sb[CHUNK1];        // 8 KB: bucket id per slot
    __shared__ int hist[NB1], lbase[NB1], lcur[NB1], gbase[NB1];
    const int tid = threadIdx.x;
    const int c0 = blockIdx.x * CHUNK1;
    const int n = (c0 + CHUNK1 <= NNZ) ? CHUNK1 : (NNZ - c0);

    for (int b = tid; b < NB1; b += 256) hist[b] = 0;
    __syncthreads();

    // load my edges (coalesced), histogram
    int2 pay[CHUNK1 / 256];
    int  pb[CHUNK1 / 256];
#pragma unroll
    for (int k = 0; k < CHUNK1 / 256; ++k) {
        int i = tid + k * 256;
        if (i < n) {
            int e = c0 + i;
            int r = rows[e];
            int b = r >> 9;
            pay[k] = make_int2(cols[e] | ((r & 511) << 18),
                               __float_as_int(vals[e]));
            pb[k] = b;
            atomicAdd(&hist[b], 1);
        } else pb[k] = -1;
    }
    __syncthreads();

    // exclusive scan over 293 buckets (single thread: ~300 adds, negligible)
    if (tid == 0) {
        int run = 0;
        for (int b = 0; b < NB1; ++b) {
            lbase[b] = run;
            lcur[b] = run;
            run += hist[b];
        }
    }
    __syncthreads();
    // global space reservation: one atomic per non-empty bucket per chunk
    for (int b = tid; b < NB1; b += 256)
        if (hist[b] > 0) gbase[b] = atomicAdd(&bcur[b], hist[b]);
    __syncthreads();

    // place into LDS, bucket-sorted
#pragma unroll
    for (int k = 0; k < CHUNK1 / 256; ++k) {
        if (pb[k] >= 0) {
            int pos = atomicAdd(&lcur[pb[k]], 1);
            stage[pos] = pay[k];
            sb[pos] = (unsigned short)pb[k];
        }
    }
    __syncthreads();

    // flush: consecutive i within a bucket -> consecutive global addresses
    for (int i = tid; i < n; i += 256) {
        int b = sb[i];
        tmp[gbase[b] + (i - lbase[b])] = stage[i];
    }
}

// ---------------------------------------------------------------------------
// P2: one block per coarse bucket. Stage the bucket's 512 row cursors in LDS,
// scatter edges to final CSR positions (write window ~175 KB, L2-resident),
// then write per-row END offsets cur[].
// ---------------------------------------------------------------------------
__global__ __launch_bounds__(256) void p2_k(const int* __restrict__ rowbase,
                                            const int2* __restrict__ tmp,
                                            int2* __restrict__ edges,
                                            int* __restrict__ cur) {
    __shared__ int rc[RPB1];
    int b = blockIdx.x;
    int tid = threadIdx.x;
    int r0 = b * RPB1;
    int nr = (r0 + RPB1 <= N_NODES) ? RPB1 : (N_NODES - r0);
    for (int t = tid; t < nr; t += 256) rc[t] = rowbase[r0 + t];
    __syncthreads();
    int beg = rowbase[r0];
    int end = rowbase[r0 + nr];   // sentinel covers last bucket
    for (int i = beg + tid; i < end; i += 256) {
        int2 w = tmp[i];
        int rl = (w.x >> 18) & 511;
        int pos = atomicAdd(&rc[rl], 1);
        edges[pos] = make_int2(w.x & 0x3FFFF, w.y);
    }
    __syncthreads();
    for (int t = tid; t < nr; t += 256) cur[r0 + t] = rc[t];
}

// ---------------------------------------------------------------------------
// Pack layer-0 sources: pE = bf16(ego), pIT = bf16(img) | bf16(txt)<<16
// ---------------------------------------------------------------------------
__global__ __launch_bounds__(256) void pack0_k(
    const float* __restrict__ user, const float* __restrict__ item,
    const float* __restrict__ image, const float* __restrict__ text,
    unsigned short* __restrict__ pE, unsigned* __restrict__ pIT) {
    size_t idx = (size_t)blockIdx.x * 256 + threadIdx.x;
    if (idx >= MATF) return;
    int row = (int)(idx >> 6);
    float e, i, t;
    if (row < USER_NUM) {
        float u = user[idx];
        e = u; i = u; t = u;
    } else {
        size_t cc = idx - (size_t)USER_NUM * EMB;
        e = item[cc]; i = image[cc]; t = text[cc];
    }
    pE[idx]  = f_to_bfu(e);
    pIT[idx] = (unsigned)f_to_bfu(i) | ((unsigned)f_to_bfu(t) << 16);
}

// ---------------------------------------------------------------------------
// Fused SpMM (3 matrices, packed bf16 sources) + leaky-relu + threefry
// dropout + l2norm + output accumulation. One wave per row; lane == dim.
// ---------------------------------------------------------------------------
__global__ __launch_bounds__(256) void spmm_post(
    const int* __restrict__ cur, const int2* __restrict__ edges,
    const unsigned short* __restrict__ sE, const unsigned* __restrict__ sIT,
    unsigned short* __restrict__ dE, unsigned* __restrict__ dIT,
    const float* __restrict__ w, float* __restrict__ out,
    unsigned ki0, unsigned ki1, unsigned kt0, unsigned kt1,
    int writeBack, int first) {
    int row = (int)((blockIdx.x * 256u + threadIdx.x) >> 6);
    int lane = threadIdx.x & 63;
    if (row >= N_NODES) return;
    int beg = __builtin_amdgcn_readfirstlane((row == 0) ? 0 : cur[row - 1]);
    int end = __builtin_amdgcn_readfirstlane(cur[row]);
    float ae = 0.f, ai = 0.f, at = 0.f;
#pragma unroll 8
    for (int i = beg; i < end; ++i) {
        int2 cv = edges[i];            // wave-uniform 8B load
        size_t cc = (size_t)cv.x * EMB + lane;
        float v = __int_as_float(cv.y);
        float xe = bfu_to_f(sE[cc]);
        unsigned it = sIT[cc];
        float xi = __uint_as_float(it << 16);
        float xt = __uint_as_float(it & 0xffff0000u);
        ae += v * xe; ai += v * xi; at += v * xt;
    }

    size_t idx = (size_t)row * EMB + lane;
    unsigned j = (unsigned)idx;

    float iv = ai >= 0.f ? ai : 0.01f * ai;      // leaky_relu
    float tv = at >= 0.f ? at : 0.01f * at;
    unsigned y0, y1;
    tf_block(ki0, ki1, 0u, j, y0, y1);
    iv = ((y0 ^ y1) >> 31) ? 0.f : iv * 2.f;     // dropout p=0.5, keep iff MSB==0
    tf_block(kt0, kt1, 0u, j, y0, y1);
    tv = ((y0 ^ y1) >> 31) ? 0.f : tv * 2.f;

    if (writeBack) {                              // next layer's SpMM inputs
        dE[idx]  = f_to_bfu(ae);
        dIT[idx] = (unsigned)f_to_bfu(iv) | ((unsigned)f_to_bfu(tv) << 16);
    }

    // row-wise l2 norms across the 64 lanes (full f32 values)
    float si = iv * iv, st2 = tv * tv;
#pragma unroll
    for (int m = 1; m < 64; m <<= 1) {
        si  += __shfl_xor(si, m, 64);
        st2 += __shfl_xor(st2, m, 64);
    }
    float ni = iv / fmaxf(sqrtf(si), 1e-12f);
    float nt = tv / fmaxf(sqrtf(st2), 1e-12f);

    const float inv3 = 1.0f / 3.0f;
    float contrib = (row < USER_NUM) ? ae * inv3
                                     : (w[0] * ae + w[1] * ni + w[2] * nt) * inv3;
    if (first) out[idx] = contrib;               // layer 0 overwrites (no memset)
    else       out[idx] += contrib;
}

// ---------------------------------------------------------------------------
extern "C" void kernel_launch(void* const* d_in, const int* in_sizes, int n_in,
                              void* d_out, int out_size, void* d_ws, size_t ws_size,
                              hipStream_t stream) {
    const float* user  = (const float*)d_in[0];
    const float* item  = (const float*)d_in[1];
    const float* image = (const float*)d_in[2];
    const float* text  = (const float*)d_in[3];
    const float* w     = (const float*)d_in[4];
    const float* vals  = (const float*)d_in[5];
    const int*   rows  = (const int*)d_in[6];
    const int*   cols  = (const int*)d_in[7];
    float* out = (float*)d_out;

    // workspace layout (~168 MB)
    int2* edges = (int2*)d_ws;                               // NNZ * 8B
    unsigned short* eA = (unsigned short*)(edges + NNZ);     // E ping (bf16)
    unsigned short* eB = eA + MATF;                          // E pong
    unsigned* itA = (unsigned*)(eB + MATF);                  // IT ping (2xbf16)
    unsigned* itB = itA + MATF;                              // IT pong
    int* cur     = (int*)(itB + MATF);                       // N_NODES
    int* rowbase = cur + N_NODES;                            // N_NODES + 1
    int* bcur    = rowbase + (N_NODES + 2);                  // NB1
    // tmp bucket buffer aliased onto (eB, itA): dead before pack0/spmm run.
    int2* tmp = (int2*)eB;                                   // NNZ * 8B

    // ---- CSR build: per-row hist/scan + write-combined 2-pass sort ----
    hipMemsetAsync(rowbase, 0, (N_NODES + 1) * sizeof(int), stream);
    hist_row_k<<<NNZ / 256, 256, 0, stream>>>(rows, rowbase);
    scan_k<<<1, SCAN_T, 0, stream>>>(rowbase);
    binit_k<<<1, NB1, 0, stream>>>(rowbase, bcur);
    p1_k<<<(NNZ + CHUNK1 - 1) / CHUNK1, 256, 0, stream>>>(rows, cols, vals,
                                                          bcur, tmp);
    p2_k<<<NB1, 256, 0, stream>>>(rowbase, tmp, edges, cur);

    const int blocks = (int)((MATF + 255) / 256);  // 37500: one wave per row
    pack0_k<<<blocks, 256, 0, stream>>>(user, item, image, text, eA, itA);

    unsigned short* sE = eA; unsigned* sIT = itA;
    unsigned short* dE = eB; unsigned* dIT = itB;
    for (int k = 0; k < 3; ++k) {
        unsigned f0, f1, a0, a1, b0, b1;
        tf_block(0u, 42u, 0u, (unsigned)k, f0, f1);
        tf_block(f0, f1, 0u, 0u, a0, a1);
        tf_block(f0, f1, 0u, 1u, b0, b1);
        int writeBack = (k < 2) ? 1 : 0;
        spmm_post<<<blocks, 256, 0, stream>>>(
            cur, edges, sE, sIT, dE, dIT, w, out, a0, a1, b0, b1,
            writeBack, k == 0 ? 1 : 0);
        // swap ping/pong
        unsigned short* te = sE; unsigned* tit = sIT;
        sE = dE; sIT = dIT;
        dE = te; dIT = tit;
    }
}